// Round 29
// baseline (298.573 us; speedup 1.0000x reference)
//
#include <hip/hip_runtime.h>
#include <math.h>

#define DIM 66
#define NPATH 17
#define WNUM 648
#define NHID 32

typedef _Float16 h2 __attribute__((ext_vector_type(2)));

// ---------------- CG computation (device, mirrors reference exactly) ----------------

__device__ double dfact(int n){ double f=1.0; for(int i=2;i<=n;i++) f*=(double)i; return f; }

__device__ double su2_cg(int j1,int j2,int j3,int m1,int m2,int m3){
  if(m1+m2!=m3) return 0.0;
  double pre = sqrt((double)(2*j3+1)*dfact(j3+j1-j2)*dfact(j3-j1+j2)*dfact(j1+j2-j3)/dfact(j1+j2+j3+1));
  pre *= sqrt(dfact(j3+m3)*dfact(j3-m3)*dfact(j1-m1)*dfact(j1+m1)*dfact(j2-m2)*dfact(j2+m2));
  double s=0.0;
  for(int k=0;k<=j1+j2-j3;k++){
    int a0=k, a1=j1+j2-j3-k, a2=j1-m1-k, a3=j2+m2-k, a4=j3-j2+m1+k, a5=j3-j1-m2+k;
    if(a0<0||a1<0||a2<0||a3<0||a4<0||a5<0) continue;
    double d = dfact(a0)*dfact(a1)*dfact(a2)*dfact(a3)*dfact(a4)*dfact(a5);
    s += ((k&1)? -1.0:1.0)/d;
  }
  return pre*s;
}

__device__ void u_real_entry(int l, int row, int col, double& re, double& im){
  re=0.0; im=0.0;
  const double sq = 0.7071067811865476;
  int m = row - l;
  if(m>0){
    if(col==l+m) re = ((m&1)? -sq : sq);
    else if(col==l-m) re = sq;
  } else if(m==0){
    if(col==l) re = 1.0;
  } else {
    int am = -m;
    if(col==l+m) im = sq;
    else if(col==l-m) im = ((am&1)? sq : -sq);
  }
}

__constant__ int c_l1[NPATH]   = {0,0,0,1,1,1,1,1,1,1,1,1,2,2,2,2,2};
__constant__ int c_l2[NPATH]   = {0,1,2,0,1,1,1,2,0,1,2,2,0,1,2,2,2};
__constant__ int c_l3[NPATH]   = {0,1,2,1,0,1,2,1,1,1,1,2,2,1,0,1,2};
__constant__ int c_cgoff[NPATH]= {0,1,10,35,44,53,80,125,170,179,206,251,326,351,396,421,496};

__global__ void cg_init_kernel(float* __restrict__ cg_out){
  int p = blockIdx.x;
  int l1=c_l1[p], l2=c_l2[p], l3=c_l3[p];
  int n1=2*l1+1, n2=2*l2+1, n3=2*l3+1;
  int ntot=n1*n2*n3;
  __shared__ double Cc[125];
  __shared__ double red[128];
  int t=threadIdx.x;
  if(t<ntot){
    int i=t/(n2*n3), j=(t/n3)%n2, k=t%n3;
    Cc[t] = su2_cg(l1,l2,l3,i-l1,j-l2,k-l3);
  }
  __syncthreads();
  double Tre=0.0, Tim=0.0;
  if(t<ntot){
    int a=t/(n2*n3), b=(t/n3)%n2, c=t%n3;
    for(int i=0;i<n1;i++)for(int j=0;j<n2;j++)for(int k=0;k<n3;k++){
      double cc=Cc[(i*n2+j)*n3+k];
      if(cc==0.0) continue;
      double u1r,u1i,u2r,u2i,u3r,u3i;
      u_real_entry(l1,a,i,u1r,u1i); u1i=-u1i;
      u_real_entry(l2,b,j,u2r,u2i); u2i=-u2i;
      u_real_entry(l3,c,k,u3r,u3i);
      double pr=u1r*u2r-u1i*u2i, pi=u1r*u2i+u1i*u2r;
      double qr=pr*u3r-pi*u3i,   qi=pr*u3i+pi*u3r;
      Tre+=qr*cc; Tim+=qi*cc;
    }
  }
  red[t]=fabs(Tre); __syncthreads();
  for(int s=64;s>0;s>>=1){ if(t<s) red[t]+=red[t+s]; __syncthreads(); }
  double sar=red[0]; __syncthreads();
  red[t]=fabs(Tim); __syncthreads();
  for(int s=64;s>0;s>>=1){ if(t<s) red[t]+=red[t+s]; __syncthreads(); }
  double sai=red[0]; __syncthreads();
  double chosen = (sar>=sai)? Tre : Tim;
  red[t]=chosen*chosen; __syncthreads();
  for(int s=64;s>0;s>>=1){ if(t<s) red[t]+=red[t+s]; __syncthreads(); }
  double nrm=sqrt(red[0]);
  if(t<ntot) cg_out[c_cgoff[p]+t] = (float)(chosen/nrm);
}

// ------- W -> h2 pairs: wf2[row][16], fold 1/sqrt(32) -------

__global__ void wf2_pack_kernel(const float* __restrict__ w2, h2* __restrict__ wf2){
  int i=blockIdx.x*blockDim.x+threadIdx.x;
  if(i>=WNUM*16) return;
  int nr=i>>4, t2=i&15;
  const float sc = 0.17677669529663687f;
  h2 v;
  v.x = (_Float16)(w2[(2*t2  )*WNUM+nr]*sc);
  v.y = (_Float16)(w2[(2*t2+1)*WNUM+nr]*sc);
  wf2[i]=v;
}

// ------- hid2[t2][el] -------

__global__ void hid2_kernel(const float* __restrict__ e_attr, const float* __restrict__ rad_w1,
                            h2* __restrict__ hidg2, int BE){
  int el = blockIdx.x*blockDim.x+threadIdx.x;
  if(el>=BE) return;
  int t2 = blockIdx.y;
  const float* ea = e_attr + (long)el*3;
  float x=ea[0], y=ea[1], z=ea[2];
  float rn = sqrtf(x*x+y*y+z*z)+1e-8f;
  float a0 = rn*rad_w1[2*t2], a1 = rn*rad_w1[2*t2+1];
  h2 v;
  v.x = (_Float16)(a0/(1.f+expf(-a0)));
  v.y = (_Float16)(a1/(1.f+expf(-a1)));
  hidg2[(size_t)t2*BE + el] = v;
}

// ---------------- per-node linears (WRITE_RES: also write residual to out) ----------------

template<bool WRITE_RES>
__global__ void linear_kernel(const float* __restrict__ h,
  const float* __restrict__ w0i, const float* __restrict__ w1oi, const float* __restrict__ w1ei,
  const float* __restrict__ w2i, const float* __restrict__ b0i,
  const float* __restrict__ w0r, const float* __restrict__ w1or_, const float* __restrict__ w1er,
  const float* __restrict__ w2r, const float* __restrict__ b0r,
  float* __restrict__ h_in, float* __restrict__ out, int total)
{
  int idx=blockIdx.x*blockDim.x+threadIdx.x;
  if(idx>=total) return;
  int d = idx % DIM;
  long bn = idx / DIM;
  const float* hr = h + bn*(long)DIM;
  float s1=0.f, s2=0.f, o1, o2=0.f;
  if(d<12){
    #pragma unroll
    for(int u=0;u<12;u++){ float xv=hr[u]; s1+=xv*w0i[u*12+d]; if(WRITE_RES) s2+=xv*w0r[u*12+d]; }
    const float r = 0.28867513459481287f;
    o1 = s1*r + b0i[d]; if(WRITE_RES) o2 = s2*r + b0r[d];
  } else if(d<24){
    int rel=d-12, v=rel/3, i=rel%3;
    #pragma unroll
    for(int u=0;u<4;u++){ float xv=hr[12+u*3+i]; s1+=xv*w1oi[u*4+v]; if(WRITE_RES) s2+=xv*w1or_[u*4+v]; }
    o1=s1*0.5f; if(WRITE_RES) o2=s2*0.5f;
  } else if(d<36){
    int rel=d-24, v=rel/3, i=rel%3;
    #pragma unroll
    for(int u=0;u<4;u++){ float xv=hr[24+u*3+i]; s1+=xv*w1ei[u*4+v]; if(WRITE_RES) s2+=xv*w1er[u*4+v]; }
    o1=s1*0.5f; if(WRITE_RES) o2=s2*0.5f;
  } else {
    int rel=d-36, v=rel/5, i=rel%5;
    #pragma unroll
    for(int u=0;u<6;u++){ float xv=hr[36+u*5+i]; s1+=xv*w2i[u*6+v]; if(WRITE_RES) s2+=xv*w2r[u*6+v]; }
    const float r=0.4082482904638631f;
    o1=s1*r; if(WRITE_RES) o2=s2*r;
  }
  h_in[idx]=o1;
  if(WRITE_RES) out[idx]=o2;
}

// ---------------- CSR build ----------------

__global__ void count_kernel(const int* __restrict__ e_dst, int* __restrict__ cnt, int BE, int N, int E){
  int el=blockIdx.x*blockDim.x+threadIdx.x;
  if(el>=BE) return;
  int b=el/E;
  atomicAdd(&cnt[b*N+e_dst[el]], 1);
}

__global__ void scan_kernel(const int* __restrict__ cnt, int* __restrict__ off, int BN){
  __shared__ int part[1024];
  int t=threadIdx.x;
  int items=(BN+1023)>>10;
  int base=t*items;
  int s=0;
  for(int i=0;i<items;i++){ int idx=base+i; if(idx<BN) s+=cnt[idx]; }
  part[t]=s; __syncthreads();
  for(int d=1;d<1024;d<<=1){
    int v=(t>=d)?part[t-d]:0; __syncthreads();
    part[t]+=v; __syncthreads();
  }
  int run=(t==0)?0:part[t-1];
  for(int i=0;i<items;i++){ int idx=base+i; if(idx<BN){ off[idx]=run; run+=cnt[idx]; } }
}

__global__ void fill_kernel(const int* __restrict__ e_dst, const int* __restrict__ off,
                            int* __restrict__ cursor, int* __restrict__ elist, int BE, int N, int E){
  int el=blockIdx.x*blockDim.x+threadIdx.x;
  if(el>=BE) return;
  int b=el/E;
  int fd=b*N+e_dst[el];
  int pos=atomicAdd(&cursor[fd],1);
  elist[off[fd]+pos]=el;
}

// ---------------- Kernel B: fused TP per (edge, v-unit); fdot2 weight dots ----------------

template<int L1_,int L2_,int L3_,int MUL1,int MULO,int XOFF,int YOFF,int WOFF,int CGOFF>
__device__ __forceinline__ void do_path_f(const float* __restrict__ hs, const float* Y,
  const h2* __restrict__ wf2, const h2* __restrict__ hid2,
  const float* __restrict__ cgl, int v, float* acc)
{
  constexpr int N1=2*L1_+1, N2=2*L2_+1, N3=2*L3_+1;
  float M[N1*N3];
  #pragma unroll
  for(int i=0;i<N1;i++){
    #pragma unroll
    for(int k=0;k<N3;k++){
      float s=0.f;
      #pragma unroll
      for(int j=0;j<N2;j++) s += Y[YOFF+j]*cgl[CGOFF+(i*N2+j)*N3+k];
      M[i*N3+k]=s;
    }
  }
  #pragma unroll
  for(int u=0;u<MUL1;u++){
    const h2* wr = wf2 + (WOFF+u*MULO+v)*16;
    float w=0.f;
    #pragma unroll
    for(int t2=0;t2<16;t2++) w = __builtin_amdgcn_fdot2(wr[t2], hid2[t2], w, false);
    #pragma unroll
    for(int k=0;k<N3;k++){
      float z=0.f;
      #pragma unroll
      for(int i=0;i<N1;i++) z += hs[XOFF+u*N1+i]*M[i*N3+k];
      acc[k] += z*w;
    }
  }
}

template<bool USE_ATOMIC>
__global__ __launch_bounds__(256) void tp_out_kernel(
  const float* __restrict__ h_in, const int* __restrict__ e_src, const int* __restrict__ e_dst,
  const float* __restrict__ e_attr, const h2* __restrict__ hidg2, const h2* __restrict__ wf2,
  const float* __restrict__ cg, float* __restrict__ outat, _Float16* __restrict__ msgh,
  int BE, int N, int E)
{
  __shared__ float cgl[640];
  for(int i=threadIdx.x;i<621;i+=256) cgl[i]=cg[i];
  __syncthreads();
  long el = (long)blockIdx.y*256 + threadIdx.x;
  if(el>=BE) return;
  int vu = blockIdx.x;
  size_t BEs = (size_t)BE;
  int b = (int)(el / E);
  int src = e_src[el];
  const float* ea = e_attr + el*3;
  float x=ea[0], y=ea[1], z=ea[2];
  float rn = sqrtf(x*x+y*y+z*z) + 1e-8f;
  float xh=x/rn, yh=y/rn, zh=z/rn;
  float Y[9];
  const float s3=1.7320508075688772f, s5=2.23606797749979f, s15=3.872983346207417f;
  Y[0]=1.f; Y[1]=s3*yh; Y[2]=s3*zh; Y[3]=s3*xh;
  Y[4]=s15*xh*yh; Y[5]=s15*yh*zh; Y[6]=0.5f*s5*(3.f*zh*zh-1.f);
  Y[7]=s15*xh*zh; Y[8]=0.5f*s15*(xh*xh-yh*yh);
  h2 hid2[16];
  #pragma unroll
  for(int t2=0;t2<16;t2++) hid2[t2] = hidg2[(size_t)t2*BEs + el];
  const float* hs = h_in + ((long)b*N + src)*DIM;
  float* op = USE_ATOMIC ? (outat + ((long)b*N + e_dst[el])*DIM) : nullptr;
  float acc[5];
  #pragma unroll
  for(int i=0;i<5;i++) acc[i]=0.f;

  if(vu<12){
    int v=vu;
    do_path_f<0,0,0,12,12,  0,0,   0,   0>(hs,Y,wf2,hid2,cgl,v,acc);
    do_path_f<1,1,0, 4,12, 12,1, 280,  44>(hs,Y,wf2,hid2,cgl,v,acc);
    do_path_f<2,2,0, 6,12, 36,4, 516, 396>(hs,Y,wf2,hid2,cgl,v,acc);
    float r = acc[0]*0.21320071635561044f;
    if(USE_ATOMIC) unsafeAtomicAdd(&op[v], r);
    else msgh[(size_t)v*BEs + el] = (_Float16)r;
  } else if(vu<16){
    int v=vu-12;
    do_path_f<0,1,1,12, 4,  0,1, 144,   1>(hs,Y,wf2,hid2,cgl,v,acc);
    do_path_f<1,0,1, 4, 4, 12,0, 264,  35>(hs,Y,wf2,hid2,cgl,v,acc);
    do_path_f<1,2,1, 4, 4, 12,4, 368, 125>(hs,Y,wf2,hid2,cgl,v,acc);
    do_path_f<1,1,1, 4, 4, 24,1, 400, 179>(hs,Y,wf2,hid2,cgl,v,acc);
    do_path_f<2,1,1, 6, 4, 36,1, 492, 351>(hs,Y,wf2,hid2,cgl,v,acc);
    #pragma unroll
    for(int k=0;k<3;k++){
      float r = acc[k]*0.31622776601683794f;
      int d = 12+v*3+k;
      if(USE_ATOMIC) unsafeAtomicAdd(&op[d], r);
      else msgh[(size_t)d*BEs + el] = (_Float16)r;
    }
  } else if(vu<20){
    int v=vu-16;
    do_path_f<1,1,1, 4, 4, 12,1, 328,  53>(hs,Y,wf2,hid2,cgl,v,acc);
    do_path_f<1,0,1, 4, 4, 24,0, 384, 170>(hs,Y,wf2,hid2,cgl,v,acc);
    do_path_f<1,2,1, 4, 4, 24,4, 416, 206>(hs,Y,wf2,hid2,cgl,v,acc);
    do_path_f<2,2,1, 6, 4, 36,4, 588, 421>(hs,Y,wf2,hid2,cgl,v,acc);
    #pragma unroll
    for(int k=0;k<3;k++){
      float r = acc[k]*0.4082482904638631f;
      int d = 24+v*3+k;
      if(USE_ATOMIC) unsafeAtomicAdd(&op[d], r);
      else msgh[(size_t)d*BEs + el] = (_Float16)r;
    }
  } else {
    int v=vu-20;
    do_path_f<0,2,2,12, 6,  0,4, 192,  10>(hs,Y,wf2,hid2,cgl,v,acc);
    do_path_f<1,1,2, 4, 6, 12,1, 344,  80>(hs,Y,wf2,hid2,cgl,v,acc);
    do_path_f<1,2,2, 4, 6, 24,4, 432, 251>(hs,Y,wf2,hid2,cgl,v,acc);
    do_path_f<2,0,2, 6, 6, 36,0, 456, 326>(hs,Y,wf2,hid2,cgl,v,acc);
    do_path_f<2,2,2, 6, 6, 36,4, 612, 496>(hs,Y,wf2,hid2,cgl,v,acc);
    #pragma unroll
    for(int k=0;k<5;k++){
      float r = acc[k]*0.3952847075210474f;
      int d = 36+v*5+k;
      if(USE_ATOMIC) unsafeAtomicAdd(&op[d], r);
      else msgh[(size_t)d*BEs + el] = (_Float16)r;
    }
  }
}

// ---------------- transpose msgh[d][BE] -> msgT[el][66] (f16, LDS-tiled) ----------------

__global__ __launch_bounds__(256) void msg_tr_kernel(
  const _Float16* __restrict__ msgh, _Float16* __restrict__ msgT, int BE)
{
  __shared__ _Float16 tile[DIM*66];
  long e0 = (long)blockIdx.x*64;
  for(int i=threadIdx.x;i<DIM*64;i+=256){
    int d=i>>6, e=i&63;
    long el=e0+e;
    tile[d*66+e] = (el<BE)? msgh[(size_t)d*BE+el] : (_Float16)0.f;
  }
  __syncthreads();
  for(int i=threadIdx.x;i<64*DIM;i+=256){
    int e=i/DIM, d=i-e*DIM;
    long el=e0+e;
    if(el<BE) msgT[(size_t)el*DIM+d] = tile[d*66+e];
  }
}

// ---------------- gather2 + fused residual + norm_act: one WAVE per node ----------------

__global__ __launch_bounds__(256) void gather2_kernel(
  const _Float16* __restrict__ msgT, const int* __restrict__ cnt, const int* __restrict__ off,
  const int* __restrict__ elist, const float* __restrict__ h,
  const float* __restrict__ w0r, const float* __restrict__ w1or_, const float* __restrict__ w1er,
  const float* __restrict__ w2r, const float* __restrict__ b0r,
  float* __restrict__ out, int BN)
{
  __shared__ float tot[4][DIM];
  int wave = threadIdx.x>>6, lane = threadIdx.x&63;
  long node = (long)blockIdx.x*4 + wave;
  if(node>=BN) return;
  int c = cnt[node], o = off[node];
  float s0=0.f, s1=0.f;
  for(int i=0;i<c;i++){
    int el = elist[o+i];
    const _Float16* mr = msgT + (size_t)el*DIM;
    s0 += (float)mr[lane];
    if(lane<2) s1 += (float)mr[64+lane];
  }
  const float* hr = h + node*(long)DIM;

  // residual for channel d (computed in-wave; weights L1-resident)
  auto resd = [&](int d)->float{
    float s2=0.f;
    if(d<12){
      #pragma unroll
      for(int u=0;u<12;u++) s2 += hr[u]*w0r[u*12+d];
      return s2*0.28867513459481287f + b0r[d];
    } else if(d<24){
      int rel=d-12, v=rel/3, i=rel%3;
      #pragma unroll
      for(int u=0;u<4;u++) s2 += hr[12+u*3+i]*w1or_[u*4+v];
      return s2*0.5f;
    } else if(d<36){
      int rel=d-24, v=rel/3, i=rel%3;
      #pragma unroll
      for(int u=0;u<4;u++) s2 += hr[24+u*3+i]*w1er[u*4+v];
      return s2*0.5f;
    } else {
      int rel=d-36, v=rel/5, i=rel%5;
      #pragma unroll
      for(int u=0;u<6;u++) s2 += hr[36+u*5+i]*w2r[u*6+v];
      return s2*0.4082482904638631f;
    }
  };

  float t0 = resd(lane) + s0;
  tot[wave][lane] = t0;
  float t1 = 0.f;
  if(lane<2){ t1 = resd(64+lane) + s1; tot[wave][64+lane] = t1; }
  // wave-lockstep: single-wave LDS writes visible to same wave's reads
  float* op = out + node*(long)DIM;
  {
    int d = lane, offc, len;
    if(d<12){ offc=d; len=1; }
    else if(d<24){ offc=12+((d-12)/3)*3; len=3; }
    else if(d<36){ offc=24+((d-24)/3)*3; len=3; }
    else { offc=36+((d-36)/5)*5; len=5; }
    float ss=0.f;
    for(int i=0;i<len;i++){ float v=tot[wave][offc+i]; ss+=v*v; }
    float n = sqrtf(ss+1e-12f);
    float sc = 1.f/(1.f+expf(-n));
    op[d] = t0*sc;
  }
  if(lane<2){
    int d = 64+lane;
    float ss=0.f;
    for(int i=0;i<5;i++){ float v=tot[wave][61+i]; ss+=v*v; }
    float n = sqrtf(ss+1e-12f);
    float sc = 1.f/(1.f+expf(-n));
    op[d] = t1*sc;
  }
}

// ---------------- norm_act (fallback path only) ----------------

__global__ void norm_act_kernel(float* __restrict__ out, int total){
  int idx=blockIdx.x*blockDim.x+threadIdx.x;
  if(idx>=total) return;
  int c = idx % 26; long bn = idx / 26;
  int off, len;
  if(c<12){ off=c; len=1; }
  else if(c<16){ off=12+(c-12)*3; len=3; }
  else if(c<20){ off=24+(c-16)*3; len=3; }
  else { off=36+(c-20)*5; len=5; }
  float* p = out + bn*(long)DIM + off;
  float sum=0.f;
  for(int i=0;i<len;i++){ float v=p[i]; sum+=v*v; }
  float n = sqrtf(sum+1e-12f);
  float sc = 1.f/(1.f+expf(-n));
  for(int i=0;i<len;i++) p[i]*=sc;
}

// ---------------- launch ----------------

extern "C" void kernel_launch(void* const* d_in, const int* in_sizes, int n_in,
                              void* d_out, int out_size, void* d_ws, size_t ws_size,
                              hipStream_t stream)
{
  const float* h       = (const float*)d_in[0];
  const int*   e_src   = (const int*)  d_in[1];
  const int*   e_dst   = (const int*)  d_in[2];
  const float* e_attr  = (const float*)d_in[3];
  const float* lw0     = (const float*)d_in[4];
  const float* lw1o    = (const float*)d_in[5];
  const float* lw1e    = (const float*)d_in[6];
  const float* lw2     = (const float*)d_in[7];
  const float* lb0     = (const float*)d_in[8];
  const float* rw0     = (const float*)d_in[9];
  const float* rw1o    = (const float*)d_in[10];
  const float* rw1e    = (const float*)d_in[11];
  const float* rw2     = (const float*)d_in[12];
  const float* rb0     = (const float*)d_in[13];
  const float* rad_w1  = (const float*)d_in[14];
  const float* rad_w2  = (const float*)d_in[15];

  const int B  = 2;
  const int BE = in_sizes[1];
  const int E  = BE / B;
  const int BN = in_sizes[0] / DIM;
  const int N  = BN / B;

  float* ws   = (float*)d_ws;
  float* h_in = ws;                                   // BN*DIM f32
  float* cg   = ws + (size_t)BN*DIM;                  // 640 f32
  h2*    wf2  = (h2*)(cg + 640);                      // WNUM*16 h2
  h2*    hidg2= wf2 + (size_t)WNUM*16;                // 16*BE h2
  _Float16* msgh = (_Float16*)(hidg2 + (size_t)16*BE);// DIM*BE f16
  _Float16* msgT = msgh + (size_t)DIM*BE;             // BE*DIM f16
  int*   cnt  = (int*)(msgT + (size_t)BE*DIM);
  int*   cur  = cnt + BN;
  int*   offp = cur + BN;
  int*   elist= offp + BN;

  size_t need_f = (size_t)BN*DIM + 640 + (size_t)WNUM*16 + (size_t)16*BE
                + (size_t)DIM*BE + 3*(size_t)BN + (size_t)BE;
  bool csr_ok = (ws_size/4) >= need_f + 1024;

  cg_init_kernel<<<NPATH, 128, 0, stream>>>(cg);
  int wfn = WNUM*16;
  wf2_pack_kernel<<<(wfn+255)/256, 256, 0, stream>>>(rad_w2, wf2);
  dim3 hgrid((BE+255)/256, 16);
  hid2_kernel<<<hgrid, 256, 0, stream>>>(e_attr, rad_w1, hidg2, BE);
  int totL = BN*DIM;
  if(csr_ok){
    linear_kernel<false><<<(totL+255)/256, 256, 0, stream>>>(h, lw0, lw1o, lw1e, lw2, lb0,
                                                             rw0, rw1o, rw1e, rw2, rb0,
                                                             h_in, (float*)d_out, totL);
    hipMemsetAsync(cnt, 0, 2*(size_t)BN*sizeof(int), stream);
    count_kernel<<<(BE+255)/256, 256, 0, stream>>>(e_dst, cnt, BE, N, E);
    scan_kernel<<<1, 1024, 0, stream>>>(cnt, offp, BN);
    fill_kernel<<<(BE+255)/256, 256, 0, stream>>>(e_dst, offp, cur, elist, BE, N, E);
    dim3 bgrid(26, (BE+255)/256);
    tp_out_kernel<false><<<bgrid, 256, 0, stream>>>(h_in, e_src, e_dst, e_attr,
                                                    hidg2, wf2, cg, nullptr, msgh, BE, N, E);
    msg_tr_kernel<<<(BE+63)/64, 256, 0, stream>>>(msgh, msgT, BE);
    gather2_kernel<<<(BN+3)/4, 256, 0, stream>>>(msgT, cnt, offp, elist,
                                                 h, rw0, rw1o, rw1e, rw2, rb0,
                                                 (float*)d_out, BN);
  } else {
    linear_kernel<true><<<(totL+255)/256, 256, 0, stream>>>(h, lw0, lw1o, lw1e, lw2, lb0,
                                                            rw0, rw1o, rw1e, rw2, rb0,
                                                            h_in, (float*)d_out, totL);
    dim3 bgrid(26, (BE+255)/256);
    tp_out_kernel<true><<<bgrid, 256, 0, stream>>>(h_in, e_src, e_dst, e_attr,
                                                   hidg2, wf2, cg, (float*)d_out, msgh, BE, N, E);
    int totN = BN*26;
    norm_act_kernel<<<(totN+255)/256, 256, 0, stream>>>((float*)d_out, totN);
  }
}